// Round 9
// baseline (4386.027 us; speedup 1.0000x reference)
//
#include <hip/hip_runtime.h>
#include <hip/hip_bf16.h>
#include <cstdint>

#define NB 8192
#define TSTEPS 48

typedef __hip_bfloat16 bf16;
typedef short bf16x8 __attribute__((ext_vector_type(8)));
typedef float f32x4 __attribute__((ext_vector_type(4)));

__device__ __forceinline__ float sigf(float x) { return 1.0f / (1.0f + __expf(-x)); }
__device__ __forceinline__ float tanhf_fast(float x) { return 2.0f / (1.0f + __expf(-2.0f * x)) - 1.0f; }

// async global->LDS, 16B/lane. LDS dest = wave-uniform base + lane*16 (m104).
__device__ __forceinline__ void gld_lds16(const void* g, void* l) {
  typedef const __attribute__((address_space(1))) unsigned int* gp_t;
  typedef __attribute__((address_space(3))) unsigned int* lp_t;
  __builtin_amdgcn_global_load_lds(reinterpret_cast<gp_t>(reinterpret_cast<uintptr_t>(g)),
                                   reinterpret_cast<lp_t>(reinterpret_cast<uintptr_t>(l)),
                                   16, 0, 0);
}

// gate-interleaved packed gate-column order: p = (u>>4)*64 + g*16 + (u&15)
// -> N-tile j of wave w is gate (j&3) of unit group 2w+(j>>2); thread's 4 gate frags
//    for unit u = (2w + j>>2)*16 + l16 line up for a register-local cell.
__device__ __forceinline__ int orig_row_p(int p) {
  int ug = p >> 6, g = (p >> 4) & 3, s = p & 15;
  return g * 256 + ug * 16 + s;  // original row j = g*256 + u
}

// ---------------- feats precompute: [T, N, 32] bf16 (linear chunks; cols 16..31 zero) ----
__global__ void feats_kernel(const float* __restrict__ x, const float* __restrict__ coords,
                             const float* __restrict__ env, const float* __restrict__ areas,
                             const float* __restrict__ bird, bf16* __restrict__ feats) {
  int idx = blockIdx.x * 256 + threadIdx.x;  // = t*NB + n
  int n = idx & (NB - 1);
  int t = idx >> 13;
  __align__(16) bf16 v[32];
  v[0] = __float2bfloat16(x[n * TSTEPS + t]);
  v[1] = __float2bfloat16(coords[n * 2 + 0]);
  v[2] = __float2bfloat16(coords[n * 2 + 1]);
#pragma unroll
  for (int e = 0; e < 10; ++e) v[3 + e] = __float2bfloat16(env[(n * 10 + e) * TSTEPS + t]);
  v[13] = __float2bfloat16(areas[n]);
  v[14] = __float2bfloat16(bird[(n * 2 + 0) * TSTEPS + t]);
  v[15] = __float2bfloat16(bird[(n * 2 + 1) * TSTEPS + t]);
#pragma unroll
  for (int f = 16; f < 32; ++f) v[f] = __float2bfloat16(0.0f);
  bf16* dst = feats + (size_t)idx * 32;
#pragma unroll
  for (int c = 0; c < 4; ++c) ((bf16x8*)dst)[c] = ((const bf16x8*)v)[c];
}

// ---------------- weight packing: per-wave frag-linear order for direct L2->VGPR loads ----
// PWA[w][kb][j][lane][e] (w<8, kb<9, j<8, lane<64, e<8): element = WA[p][k] with
// p = w*128 + j*16 + (lane&15) (gate-interleaved row), k = kb*32 + (lane>>4)*8 + e.
// Per (w,kb,j) = 1KB contiguous -> each wave's 8 frag loads/iter are perfectly coalesced.
__global__ void packPWA(const float* __restrict__ W_hh0, const float* __restrict__ W_ih0,
                        const float* __restrict__ W_in, bf16* __restrict__ PWA) {
  int idx = blockIdx.x * 256 + threadIdx.x;  // < 8*9*8*64*8 = 294912
  int w = idx / 36864, r = idx - w * 36864;
  int kb = r >> 12, j = (r >> 9) & 7, lane = (r >> 3) & 63, e = r & 7;
  int l16 = lane & 15, quad = lane >> 4;
  int p = w * 128 + j * 16 + l16;
  int jrow = orig_row_p(p);
  int k = kb * 32 + quad * 8 + e;
  float val = 0.0f;
  if (k < 256) {
    val = W_hh0[jrow * 256 + k];
  } else if (k < 272) {
    int f = k - 256;
    float s = 0.0f;
    for (int kk = 0; kk < 256; ++kk) s += W_ih0[jrow * 256 + kk] * W_in[kk * 16 + f];
    val = s;  // Wc0 = W_ih0 @ W_in fused input projection
  }
  PWA[idx] = __float2bfloat16(val);
}

// PWB[w][kb][j][lane][e] (kb<16): k<256 -> W_ih1 (h0 operand), else W_hh1 (h1 operand).
__global__ void packPWB(const float* __restrict__ W_ih1, const float* __restrict__ W_hh1,
                        bf16* __restrict__ PWB) {
  int idx = blockIdx.x * 256 + threadIdx.x;  // < 8*16*8*64*8 = 524288
  int w = idx >> 16, r = idx & 65535;
  int kb = r >> 12, j = (r >> 9) & 7, lane = (r >> 3) & 63, e = r & 7;
  int l16 = lane & 15, quad = lane >> 4;
  int p = w * 128 + j * 16 + l16;
  int jrow = orig_row_p(p);
  int k = kb * 32 + quad * 8 + e;
  float val = (k < 256) ? W_ih1[jrow * 256 + k] : W_hh1[jrow * 256 + (k - 256)];
  PWB[idx] = __float2bfloat16(val);
}

// bias packed [gate][unit] (== original j = g*256+u); sum ih+hh
__global__ void packBias_kernel(const float* __restrict__ b_ih, const float* __restrict__ b_hh,
                                float* __restrict__ bA, float* __restrict__ bB) {
  int idx = blockIdx.x * 256 + threadIdx.x;  // < 2048
  int layer = idx >> 10, r = idx & 1023;
  float v = b_ih[layer * 1024 + r] + b_hh[layer * 1024 + r];
  if (layer == 0) bA[r] = v; else bB[r] = v;
}

// ---------------- R9: R8 kernel + LDS > 80KB forces 1 block/CU -> VGPR budget 256 --------
// R6/R7/R8 all spilled with IDENTICAL traffic (FETCH 9.2-9.4GB, WRITE ~485MB) at caps
// 128/64/128: the allocator targets the occupancy ACHIEVABLE from LDS/threads (35KB LDS
// -> 2 blocks/CU -> 4 waves/SIMD -> 128-reg budget) and spills demand (~210) to meet it,
// ignoring launch_bounds. Scratch stream evicts the 1.6MB weight set from L2 -> ~50% of
// the 19.7GB weight demand misses to HBM -> latency-bound at 2.3TB/s.
// Fix: 48KB dead LDS array (kept via opaque guard) -> 85KB/block -> only 1 block/CU fits
// -> allocator target = 2 waves/SIMD -> 256-reg budget -> demand ~210 fits, ZERO spill.
__global__ __launch_bounds__(512, 1) void lstm_all(
    const bf16* __restrict__ feats, const bf16* __restrict__ PWA,
    const bf16* __restrict__ PWB, const float* __restrict__ bA,
    const float* __restrict__ bB, float* __restrict__ out) {
  __shared__ __align__(16) bf16 h0s[32 * 264];
  __shared__ __align__(16) bf16 h1s[32 * 264];
  __shared__ __align__(16) bf16 fts[32 * 32];
  __shared__ __align__(16) bf16 spare[24576];  // 48KB occupancy limiter (never executed use)

  const int tid = threadIdx.x;
  const int wid = tid >> 6, lane = tid & 63;
  const int quad = lane >> 4, l16 = lane & 15;
  const int rowbase = blockIdx.x * 32;

  // zero initial h state (c zeroed in regs)
  for (int i = tid; i < 32 * 264; i += 512) {
    h0s[i] = __float2bfloat16(0.0f);
    h1s[i] = __float2bfloat16(0.0f);
  }
  // stage feats t=0 (2KB, wave 0)
  if (wid == 0) {
    const bf16* f = feats + (size_t)rowbase * 32 + lane * 8;
    gld_lds16(f, fts);
    gld_lds16(f + 512, fts + 512);
  }
  __syncthreads();  // vmcnt drain -> fts + zeros published

  // per-lane bias regs: bs[ug*4+g] for unit u = (2*wid+ug)*16+l16
  float bsA[8], bsB[8];
#pragma unroll
  for (int ug = 0; ug < 2; ++ug)
#pragma unroll
    for (int g = 0; g < 4; ++g) {
      int u = (2 * wid + ug) * 16 + l16;
      bsA[ug * 4 + g] = bA[g * 256 + u];
      bsB[ug * 4 + g] = bB[g * 256 + u];
    }

  float c0r[16], c1r[16];
#pragma unroll
  for (int i = 0; i < 16; ++i) { c0r[i] = 0.f; c1r[i] = 0.f; }

  const int loff = lane * 8;  // 16B/lane within a 1KB frag group
  const bf16* wA = PWA + (size_t)wid * 36864 + loff;
  const bf16* wB = PWB + (size_t)wid * 65536 + loff;
  float* out_h0 = out;
  float* out_h1 = out + (size_t)NB * 256;
  float* out_c0 = out + (size_t)2 * NB * 256;
  float* out_c1 = out + (size_t)3 * NB * 256;

  f32x4 acc[2][8];
  bf16x8 bw[2][8];

  // register-local cell: thread's 8 N-frags = 4 gates x 2 unit-groups of unit u
  auto cell = [&](float* cr, bf16* hs, const float* bs, float* oh, float* oc, int last) {
#pragma unroll
    for (int m = 0; m < 2; ++m)
#pragma unroll
      for (int ug = 0; ug < 2; ++ug)
#pragma unroll
        for (int rr = 0; rr < 4; ++rr) {
          const int n = m * 16 + quad * 4 + rr;
          const int u = (2 * wid + ug) * 16 + l16;
          float gi = sigf(acc[m][ug * 4 + 0][rr] + bs[ug * 4 + 0]);
          float gf = sigf(acc[m][ug * 4 + 1][rr] + bs[ug * 4 + 1]);
          float gg = tanhf_fast(acc[m][ug * 4 + 2][rr] + bs[ug * 4 + 2]);
          float go = sigf(acc[m][ug * 4 + 3][rr] + bs[ug * 4 + 3]);
          const int ci = m * 8 + ug * 4 + rr;
          float cn = gf * cr[ci] + gi * gg;
          float hn = go * tanhf_fast(cn);
          cr[ci] = cn;
          hs[n * 264 + u] = __float2bfloat16(hn);
          if (last) {
            size_t gi2 = (size_t)(rowbase + n) * 256 + u;
            oh[gi2] = hn;
            oc[gi2] = cn;
          }
        }
  };

  for (int t = 0; t < TSTEPS; ++t) {
    const int last = (t == TSTEPS - 1);
    // ---- layer 0: gates = [h0(t-1) | feats_t] @ WA^T (K = 9x32) ----
#pragma unroll
    for (int m = 0; m < 2; ++m)
#pragma unroll
      for (int j = 0; j < 8; ++j) acc[m][j] = f32x4{0.f, 0.f, 0.f, 0.f};
#pragma unroll
    for (int j = 0; j < 8; ++j) bw[0][j] = *(const bf16x8*)(wA + j * 512);
#pragma unroll
    for (int kb = 0; kb < 9; ++kb) {
      if (kb < 8) {
#pragma unroll
        for (int j = 0; j < 8; ++j)
          bw[(kb + 1) & 1][j] = *(const bf16x8*)(wA + (kb + 1) * 4096 + j * 512);
      } else {
#pragma unroll
        for (int j = 0; j < 8; ++j)  // cross-GEMM prefetch: layer-1 kb=0 frags
          bw[1][j] = *(const bf16x8*)(wB + j * 512);
      }
      bf16x8 af[2];
      if (kb < 8) {
#pragma unroll
        for (int m = 0; m < 2; ++m)
          af[m] = *(const bf16x8*)(h0s + (m * 16 + l16) * 264 + kb * 32 + quad * 8);
      } else {
#pragma unroll
        for (int m = 0; m < 2; ++m)
          af[m] = *(const bf16x8*)(fts + (m * 16 + l16) * 32 + quad * 8);
      }
      __builtin_amdgcn_s_setprio(1);
#pragma unroll
      for (int m = 0; m < 2; ++m)
#pragma unroll
        for (int j = 0; j < 8; ++j)
          acc[m][j] = __builtin_amdgcn_mfma_f32_16x16x32_bf16(af[m], bw[kb & 1][j], acc[m][j], 0, 0, 0);
      __builtin_amdgcn_s_setprio(0);
    }
    __syncthreads();  // all waves done reading h0(t-1)/fts (drains bw[1] prefetch too)
    cell(c0r, h0s, bsA, out_h0, out_c0, last);
    __syncthreads();  // h0(t) published

    // ---- layer 1: gates = [h0(t) | h1(t-1)] @ WB^T (K = 16x32); bw[1] holds kb=0 ----
#pragma unroll
    for (int m = 0; m < 2; ++m)
#pragma unroll
      for (int j = 0; j < 8; ++j) acc[m][j] = f32x4{0.f, 0.f, 0.f, 0.f};
#pragma unroll
    for (int kb = 0; kb < 16; ++kb) {
      if (kb < 15) {
#pragma unroll
        for (int j = 0; j < 8; ++j)
          bw[kb & 1][j] = *(const bf16x8*)(wB + (kb + 1) * 4096 + j * 512);
      }
      bf16x8 af[2];
      if (kb < 8) {
#pragma unroll
        for (int m = 0; m < 2; ++m)
          af[m] = *(const bf16x8*)(h0s + (m * 16 + l16) * 264 + kb * 32 + quad * 8);
      } else {
#pragma unroll
        for (int m = 0; m < 2; ++m)
          af[m] = *(const bf16x8*)(h1s + (m * 16 + l16) * 264 + (kb - 8) * 32 + quad * 8);
      }
      __builtin_amdgcn_s_setprio(1);
#pragma unroll
      for (int m = 0; m < 2; ++m)
#pragma unroll
        for (int j = 0; j < 8; ++j)
          acc[m][j] = __builtin_amdgcn_mfma_f32_16x16x32_bf16(af[m], bw[(kb + 1) & 1][j], acc[m][j], 0, 0, 0);
      __builtin_amdgcn_s_setprio(0);
    }
    // stage feats t+1 (drained by the next barrier's vmcnt(0); read next step)
    if (t < TSTEPS - 1 && wid == 0) {
      const bf16* f = feats + ((size_t)(t + 1) * NB + rowbase) * 32 + lane * 8;
      gld_lds16(f, fts);
      gld_lds16(f + 512, fts + 512);
    }
    __syncthreads();  // h1(t-1) reads done; fts(t+1) published
    cell(c1r, h1s, bsB, out_h1, out_c1, last);
    __syncthreads();  // h1(t) published for next step
  }

  // opaque never-true use of `spare` so the 48KB LDS allocation survives DCE
  // (out is never null, but the compiler cannot prove it for a kernel arg)
  if (out == nullptr) {
    spare[tid] = h0s[tid];
    __syncthreads();
    out_h0[0] = __bfloat162float(spare[tid]);
  }
}

extern "C" void kernel_launch(void* const* d_in, const int* in_sizes, int n_in,
                              void* d_out, int out_size, void* d_ws, size_t ws_size,
                              hipStream_t stream) {
  const float* x = (const float*)d_in[0];
  const float* coords = (const float*)d_in[1];
  const float* env = (const float*)d_in[2];
  const float* areas = (const float*)d_in[3];
  const float* bird = (const float*)d_in[4];
  const float* W_in = (const float*)d_in[5];
  const float* W_ih = (const float*)d_in[6];  // [2,1024,256]
  const float* W_hh = (const float*)d_in[7];  // [2,1024,256]
  const float* b_ih = (const float*)d_in[8];  // [2,1024]
  const float* b_hh = (const float*)d_in[9];  // [2,1024]
  float* out = (float*)d_out;

  const size_t MB = 1 << 20;
  char* w0 = (char*)d_ws;
  // layout: [feats 24MB][PWA 576KB @24MB][PWB 1MB @26MB][bA @28MB][bB @28MB+4K]
  bf16* feats = (bf16*)(w0);
  bf16* PWA = (bf16*)(w0 + 24 * MB);
  bf16* PWB = (bf16*)(w0 + 26 * MB);
  float* bA = (float*)(w0 + 28 * MB);
  float* bB = (float*)(w0 + 28 * MB + 4096);

  feats_kernel<<<(NB * TSTEPS) / 256, 256, 0, stream>>>(x, coords, env, areas, bird, feats);
  packPWA<<<294912 / 256, 256, 0, stream>>>(W_hh, W_ih, W_in, PWA);
  packPWB<<<524288 / 256, 256, 0, stream>>>(W_ih + 1024 * 256, W_hh + 1024 * 256, PWB);
  packBias_kernel<<<2048 / 256, 256, 0, stream>>>(b_ih, b_hh, bA, bB);

  lstm_all<<<256, 512, 0, stream>>>(feats, PWA, PWB, bA, bB, out);
}

// Round 11
// 4306.845 us; speedup vs baseline: 1.0184x; 1.0184x over previous
//
#include <hip/hip_runtime.h>
#include <hip/hip_bf16.h>
#include <cstdint>

#define NB 8192
#define TSTEPS 48
#define HSTR 660  // h-tile LDS row stride (elems): 2x42.2KB pads LDS to ~86.5KB -> 1 block/CU

typedef __hip_bfloat16 bf16;
typedef short bf16x8 __attribute__((ext_vector_type(8)));
typedef float f32x4 __attribute__((ext_vector_type(4)));

__device__ __forceinline__ float sigf(float x) { return 1.0f / (1.0f + __expf(-x)); }
__device__ __forceinline__ float tanhf_fast(float x) { return 2.0f / (1.0f + __expf(-2.0f * x)) - 1.0f; }

// async global->LDS, 16B/lane. LDS dest = wave-uniform base + lane*16 (m104).
__device__ __forceinline__ void gld_lds16(const void* g, void* l) {
  typedef const __attribute__((address_space(1))) unsigned int* gp_t;
  typedef __attribute__((address_space(3))) unsigned int* lp_t;
  __builtin_amdgcn_global_load_lds(reinterpret_cast<gp_t>(reinterpret_cast<uintptr_t>(g)),
                                   reinterpret_cast<lp_t>(reinterpret_cast<uintptr_t>(l)),
                                   16, 0, 0);
}

// gate-interleaved packed gate-column order: p = (u>>4)*64 + g*16 + (u&15)
// -> wave w (of 16) owns packed cols [64w, 64w+64) = units [16w,16w+16) x 4 gates;
//    thread's 4 j-frags = gates i,f,g,o of unit u = w*16 + (lane&15).
__device__ __forceinline__ int orig_row_p(int p) {
  int ug = p >> 6, g = (p >> 4) & 3, s = p & 15;
  return g * 256 + ug * 16 + s;  // original row j = g*256 + u
}

// ---------------- feats precompute: [T, N, 32] bf16 (linear chunks; cols 16..31 zero) ----
__global__ void feats_kernel(const float* __restrict__ x, const float* __restrict__ coords,
                             const float* __restrict__ env, const float* __restrict__ areas,
                             const float* __restrict__ bird, bf16* __restrict__ feats) {
  int idx = blockIdx.x * 256 + threadIdx.x;  // = t*NB + n
  int n = idx & (NB - 1);
  int t = idx >> 13;
  __align__(16) bf16 v[32];
  v[0] = __float2bfloat16(x[n * TSTEPS + t]);
  v[1] = __float2bfloat16(coords[n * 2 + 0]);
  v[2] = __float2bfloat16(coords[n * 2 + 1]);
#pragma unroll
  for (int e = 0; e < 10; ++e) v[3 + e] = __float2bfloat16(env[(n * 10 + e) * TSTEPS + t]);
  v[13] = __float2bfloat16(areas[n]);
  v[14] = __float2bfloat16(bird[(n * 2 + 0) * TSTEPS + t]);
  v[15] = __float2bfloat16(bird[(n * 2 + 1) * TSTEPS + t]);
#pragma unroll
  for (int f = 16; f < 32; ++f) v[f] = __float2bfloat16(0.0f);
  bf16* dst = feats + (size_t)idx * 32;
#pragma unroll
  for (int c = 0; c < 4; ++c) ((bf16x8*)dst)[c] = ((const bf16x8*)v)[c];
}

// ---------------- weight packing: per-wave frag-linear order for direct L2->VGPR loads ----
// PWA[w][kb][j][lane][e] (w<16, kb<9, j<4, lane<64, e<8): element = WA[p][k] with
// p = w*64 + j*16 + (lane&15) (gate-interleaved row), k = kb*32 + (lane>>4)*8 + e.
// Per (w,kb,j) = 1KB contiguous -> each wave's 4 frag loads/iter are perfectly coalesced.
__global__ void packPWA(const float* __restrict__ W_hh0, const float* __restrict__ W_ih0,
                        const float* __restrict__ W_in, bf16* __restrict__ PWA) {
  int idx = blockIdx.x * 256 + threadIdx.x;  // < 16*9*4*64*8 = 294912
  int w = idx / 18432, r = idx - w * 18432;  // 18432 = 9*2048
  int kb = r >> 11, rr = r & 2047;
  int j = rr >> 9, lane = (rr >> 3) & 63, e = rr & 7;
  int l16 = lane & 15, quad = lane >> 4;
  int p = w * 64 + j * 16 + l16;
  int jrow = orig_row_p(p);
  int k = kb * 32 + quad * 8 + e;
  float val = 0.0f;
  if (k < 256) {
    val = W_hh0[jrow * 256 + k];
  } else if (k < 272) {
    int f = k - 256;
    float s = 0.0f;
    for (int kk = 0; kk < 256; ++kk) s += W_ih0[jrow * 256 + kk] * W_in[kk * 16 + f];
    val = s;  // Wc0 = W_ih0 @ W_in fused input projection
  }
  PWA[idx] = __float2bfloat16(val);
}

// PWB[w][kb][j][lane][e] (kb<16): k<256 -> W_ih1 (h0 operand), else W_hh1 (h1 operand).
__global__ void packPWB(const float* __restrict__ W_ih1, const float* __restrict__ W_hh1,
                        bf16* __restrict__ PWB) {
  int idx = blockIdx.x * 256 + threadIdx.x;  // < 16*16*4*64*8 = 524288
  int w = idx >> 15, r = idx & 32767;  // 32768 per w
  int kb = r >> 11, rr = r & 2047;
  int j = rr >> 9, lane = (rr >> 3) & 63, e = rr & 7;
  int l16 = lane & 15, quad = lane >> 4;
  int p = w * 64 + j * 16 + l16;
  int jrow = orig_row_p(p);
  int k = kb * 32 + quad * 8 + e;
  float val = (k < 256) ? W_ih1[jrow * 256 + k] : W_hh1[jrow * 256 + (k - 256)];
  PWB[idx] = __float2bfloat16(val);
}

// bias packed [gate][unit] (== original j = g*256+u); sum ih+hh
__global__ void packBias_kernel(const float* __restrict__ b_ih, const float* __restrict__ b_hh,
                                float* __restrict__ bA, float* __restrict__ bB) {
  int idx = blockIdx.x * 256 + threadIdx.x;  // < 2048
  int layer = idx >> 10, r = idx & 1023;
  float v = b_ih[layer * 1024 + r] + b_hh[layer * 1024 + r];
  if (layer == 0) bA[r] = v; else bB[r] = v;
}

// ---------------- R11: R10 design; fts (the only global_load_lds dest) moved to LDS 0 ----
// R10's container died with no counters; only deltas vs the working R7 were LDS size and
// fts landing at offset 84480. Mitigation: declare fts FIRST so the async-DMA target sits
// below 64K; h-tiles (ds_read/ds_write only, verified >64K-safe per m201's 128KB template)
// occupy the high offsets. Design unchanged:
//   demand: 16 waves x 64 cols/wave -> acc 32 + bw 32 + af 8 + c 16 + bias 8 + addr ~20
//           = ~115 VGPR;
//   cap:    h-tiles stride-660 (2x42.2KB, USED every step -> not DCE-able) -> 86.5KB LDS
//           -> 1 block/CU physical -> allocator occupancy target 4 waves/EU -> 128 VGPR.
// 115 <= 128 -> zero spill -> weights (1.6MB/XCD) stay L2-resident.
// Floor: 19.7GB L2 weight stream @ 34.5TB/s ~= 570us.
__global__ __launch_bounds__(1024, 4) void lstm_all(
    const bf16* __restrict__ feats, const bf16* __restrict__ PWA,
    const bf16* __restrict__ PWB, const float* __restrict__ bA,
    const float* __restrict__ bB, float* __restrict__ out) {
  __shared__ __align__(16) bf16 fts[32 * 32];       // offset 0: global_load_lds target
  __shared__ __align__(16) bf16 h0s[32 * HSTR];
  __shared__ __align__(16) bf16 h1s[32 * HSTR];

  const int tid = threadIdx.x;
  const int wid = tid >> 6, lane = tid & 63;
  const int quad = lane >> 4, l16 = lane & 15;
  const int rowbase = blockIdx.x * 32;
  const int u = wid * 16 + l16;

  // zero initial h state (c zeroed in regs)
  for (int i = tid; i < 32 * HSTR; i += 1024) {
    h0s[i] = __float2bfloat16(0.0f);
    h1s[i] = __float2bfloat16(0.0f);
  }
  // stage feats t=0 (2KB, wave 0)
  if (wid == 0) {
    const bf16* f = feats + (size_t)rowbase * 32 + lane * 8;
    gld_lds16(f, fts);
    gld_lds16(f + 512, fts + 512);
  }
  __syncthreads();  // vmcnt drain -> fts + zeros published

  float bsA[4], bsB[4];
#pragma unroll
  for (int g = 0; g < 4; ++g) {
    bsA[g] = bA[g * 256 + u];
    bsB[g] = bB[g * 256 + u];
  }

  float c0r[8], c1r[8];
#pragma unroll
  for (int i = 0; i < 8; ++i) { c0r[i] = 0.f; c1r[i] = 0.f; }

  const bf16* wA = PWA + (size_t)wid * 18432 + lane * 8;
  const bf16* wB = PWB + (size_t)wid * 32768 + lane * 8;
  float* out_h0 = out;
  float* out_h1 = out + (size_t)NB * 256;
  float* out_c0 = out + (size_t)2 * NB * 256;
  float* out_c1 = out + (size_t)3 * NB * 256;

  f32x4 acc[2][4];
  bf16x8 bw[2][4];

  // register-local cell: thread's 4 j-frags = gates i,f,g,o of unit u
  auto cell = [&](float* cr, bf16* hs, const float* bs, float* oh, float* oc, int last) {
#pragma unroll
    for (int m = 0; m < 2; ++m)
#pragma unroll
      for (int rr = 0; rr < 4; ++rr) {
        const int n = m * 16 + quad * 4 + rr;
        float gi = sigf(acc[m][0][rr] + bs[0]);
        float gf = sigf(acc[m][1][rr] + bs[1]);
        float gg = tanhf_fast(acc[m][2][rr] + bs[2]);
        float go = sigf(acc[m][3][rr] + bs[3]);
        const int ci = m * 4 + rr;
        float cn = gf * cr[ci] + gi * gg;
        float hn = go * tanhf_fast(cn);
        cr[ci] = cn;
        hs[n * HSTR + u] = __float2bfloat16(hn);
        if (last) {
          size_t gi2 = (size_t)(rowbase + n) * 256 + u;
          oh[gi2] = hn;
          oc[gi2] = cn;
        }
      }
  };

  for (int t = 0; t < TSTEPS; ++t) {
    const int last = (t == TSTEPS - 1);
    // ---- layer 0: gates = [h0(t-1) | feats_t] @ WA^T (K = 9x32) ----
#pragma unroll
    for (int m = 0; m < 2; ++m)
#pragma unroll
      for (int j = 0; j < 4; ++j) acc[m][j] = f32x4{0.f, 0.f, 0.f, 0.f};
#pragma unroll
    for (int j = 0; j < 4; ++j) bw[0][j] = *(const bf16x8*)(wA + j * 512);
#pragma unroll
    for (int kb = 0; kb < 9; ++kb) {
      if (kb < 8) {
#pragma unroll
        for (int j = 0; j < 4; ++j)
          bw[(kb + 1) & 1][j] = *(const bf16x8*)(wA + (kb + 1) * 2048 + j * 512);
      } else {
#pragma unroll
        for (int j = 0; j < 4; ++j)  // cross-GEMM prefetch: layer-1 kb=0 frags
          bw[1][j] = *(const bf16x8*)(wB + j * 512);
      }
      bf16x8 af[2];
      if (kb < 8) {
#pragma unroll
        for (int m = 0; m < 2; ++m)
          af[m] = *(const bf16x8*)(h0s + (m * 16 + l16) * HSTR + kb * 32 + quad * 8);
      } else {
#pragma unroll
        for (int m = 0; m < 2; ++m)
          af[m] = *(const bf16x8*)(fts + (m * 16 + l16) * 32 + quad * 8);
      }
      __builtin_amdgcn_s_setprio(1);
#pragma unroll
      for (int m = 0; m < 2; ++m)
#pragma unroll
        for (int j = 0; j < 4; ++j)
          acc[m][j] = __builtin_amdgcn_mfma_f32_16x16x32_bf16(af[m], bw[kb & 1][j], acc[m][j], 0, 0, 0);
      __builtin_amdgcn_s_setprio(0);
    }
    __syncthreads();  // all waves done reading h0(t-1)/fts (drains bw[1] prefetch too)
    cell(c0r, h0s, bsA, out_h0, out_c0, last);
    __syncthreads();  // h0(t) published

    // ---- layer 1: gates = [h0(t) | h1(t-1)] @ WB^T (K = 16x32); bw[1] holds kb=0 ----
#pragma unroll
    for (int m = 0; m < 2; ++m)
#pragma unroll
      for (int j = 0; j < 4; ++j) acc[m][j] = f32x4{0.f, 0.f, 0.f, 0.f};
#pragma unroll
    for (int kb = 0; kb < 16; ++kb) {
      if (kb < 15) {
#pragma unroll
        for (int j = 0; j < 4; ++j)
          bw[kb & 1][j] = *(const bf16x8*)(wB + (kb + 1) * 2048 + j * 512);
      }
      bf16x8 af[2];
      if (kb < 8) {
#pragma unroll
        for (int m = 0; m < 2; ++m)
          af[m] = *(const bf16x8*)(h0s + (m * 16 + l16) * HSTR + kb * 32 + quad * 8);
      } else {
#pragma unroll
        for (int m = 0; m < 2; ++m)
          af[m] = *(const bf16x8*)(h1s + (m * 16 + l16) * HSTR + (kb - 8) * 32 + quad * 8);
      }
      __builtin_amdgcn_s_setprio(1);
#pragma unroll
      for (int m = 0; m < 2; ++m)
#pragma unroll
        for (int j = 0; j < 4; ++j)
          acc[m][j] = __builtin_amdgcn_mfma_f32_16x16x32_bf16(af[m], bw[(kb + 1) & 1][j], acc[m][j], 0, 0, 0);
      __builtin_amdgcn_s_setprio(0);
    }
    // stage feats t+1 (drained by the next barrier's vmcnt(0); read next step)
    if (t < TSTEPS - 1 && wid == 0) {
      const bf16* f = feats + ((size_t)(t + 1) * NB + rowbase) * 32 + lane * 8;
      gld_lds16(f, fts);
      gld_lds16(f + 512, fts + 512);
    }
    __syncthreads();  // h1(t-1) reads done; fts(t+1) published
    cell(c1r, h1s, bsB, out_h1, out_c1, last);
    __syncthreads();  // h1(t) published for next step
  }
}

extern "C" void kernel_launch(void* const* d_in, const int* in_sizes, int n_in,
                              void* d_out, int out_size, void* d_ws, size_t ws_size,
                              hipStream_t stream) {
  const float* x = (const float*)d_in[0];
  const float* coords = (const float*)d_in[1];
  const float* env = (const float*)d_in[2];
  const float* areas = (const float*)d_in[3];
  const float* bird = (const float*)d_in[4];
  const float* W_in = (const float*)d_in[5];
  const float* W_ih = (const float*)d_in[6];  // [2,1024,256]
  const float* W_hh = (const float*)d_in[7];  // [2,1024,256]
  const float* b_ih = (const float*)d_in[8];  // [2,1024]
  const float* b_hh = (const float*)d_in[9];  // [2,1024]
  float* out = (float*)d_out;

  const size_t MB = 1 << 20;
  char* w0 = (char*)d_ws;
  // layout: [feats 24MB][PWA 576KB @24MB][PWB 1MB @26MB][bA @28MB][bB @28MB+4K]
  bf16* feats = (bf16*)(w0);
  bf16* PWA = (bf16*)(w0 + 24 * MB);
  bf16* PWB = (bf16*)(w0 + 26 * MB);
  float* bA = (float*)(w0 + 28 * MB);
  float* bB = (float*)(w0 + 28 * MB + 4096);

  feats_kernel<<<(NB * TSTEPS) / 256, 256, 0, stream>>>(x, coords, env, areas, bird, feats);
  packPWA<<<294912 / 256, 256, 0, stream>>>(W_hh, W_ih, W_in, PWA);
  packPWB<<<524288 / 256, 256, 0, stream>>>(W_ih + 1024 * 256, W_hh + 1024 * 256, PWB);
  packBias_kernel<<<2048 / 256, 256, 0, stream>>>(b_ih, b_hh, bA, bB);

  lstm_all<<<256, 1024, 0, stream>>>(feats, PWA, PWB, bA, bB, out);
}